// Round 14
// baseline (255.405 us; speedup 1.0000x reference)
//
#include <hip/hip_runtime.h>
#include <hip/hip_bf16.h>
#include <hip/hip_fp16.h>

#define NEG_SLOPE 0.2f
#define EPSV 1e-16f
#define CAP 96            // padded CSR row capacity (deg ~ Poisson(32))
#define CHUNK 4096        // edges per pass-A build block
#define BCAP 9216         // bucket capacity in edges (mean 8163, +11 sigma)

static __device__ __forceinline__ float lrelu(float v) {
    return v > 0.0f ? v : NEG_SLOPE * v;
}
static __device__ __forceinline__ float eluf(float v) {
    return v > 0.0f ? v : (__expf(v) - 1.0f);
}

// ---- fused: [0..AB): bucket pass A | [AB..AB+GB): gemm1 + alpha1 --------------
// h written SLICE-MAJOR: h[slice][n][32] fp16, slice = channel>>5.
__global__ __launch_bounds__(256) void k_fused1(
    const float* __restrict__ x, const float* __restrict__ W,
    const float* __restrict__ a_src, const float* __restrict__ a_dst,
    const int* __restrict__ ei, int E, int N, int AB,
    __half* __restrict__ h, float* __restrict__ as, float* __restrict__ ad,
    int* __restrict__ gcur, unsigned* __restrict__ bbuf) {
    __shared__ float wl[64 * 128];
    __shared__ float xl[32 * 64];
    const int tid = threadIdx.x;

    if ((int)blockIdx.x < AB) {
        // ---- pass A: reg-cached src+dst -> count -> reserve -> run-writes ------
        int* cnt = (int*)wl;
        int* base = ((int*)wl) + 256;
        int e0 = blockIdx.x * CHUNK;
        int dreg[16], sreg[16];
#pragma unroll
        for (int jj = 0; jj < 16; ++jj) {
            int e = e0 + tid + jj * 256;
            dreg[jj] = (e < E) ? ei[E + e] : -1;
            sreg[jj] = (e < E) ? ei[e] : 0;
        }
        cnt[tid] = 0;
        __syncthreads();
#pragma unroll
        for (int jj = 0; jj < 16; ++jj)
            if (dreg[jj] >= 0) atomicAdd(&cnt[dreg[jj] >> 8], 1);
        __syncthreads();
        {
            int c = cnt[tid];
            base[tid] = c ? atomicAdd(&gcur[tid], c) : 0;
            cnt[tid] = 0;
        }
        __syncthreads();
#pragma unroll
        for (int jj = 0; jj < 16; ++jj) {
            int d = dreg[jj];
            if (d >= 0) {
                int b = d >> 8;
                int k = atomicAdd(&cnt[b], 1);
                bbuf[(size_t)b * BCAP + base[b] + k] =
                    (unsigned)sreg[jj] | ((unsigned)(d & 255) << 16);
            }
        }
        return;
    }

    // ---- gemm branch: h[32 rows x 128] = x @ W, + per-head logits --------------
    const int row0 = (blockIdx.x - AB) * 32;
    const int c0 = (tid & 31) * 4;
    const int r0 = (tid >> 5) * 4;
    float acc[4][4];
#pragma unroll
    for (int r = 0; r < 4; ++r)
#pragma unroll
        for (int c = 0; c < 4; ++c) acc[r][c] = 0.0f;

    for (int kt = 0; kt < 128; kt += 64) {
        __syncthreads();
#pragma unroll
        for (int i = tid * 4; i < 64 * 128; i += 1024)
            *(float4*)&wl[i] = *(const float4*)&W[kt * 128 + i];
#pragma unroll
        for (int i = tid * 4; i < 32 * 64; i += 1024) {
            int r = i >> 6, c = i & 63;
            int gr = row0 + r;
            float4 v = make_float4(0.f, 0.f, 0.f, 0.f);
            if (gr < N) v = *(const float4*)&x[(size_t)gr * 128 + kt + c];
            *(float4*)&xl[i] = v;
        }
        __syncthreads();
#pragma unroll 8
        for (int k = 0; k < 64; ++k) {
            float4 w4 = *(const float4*)&wl[k * 128 + c0];
#pragma unroll
            for (int r = 0; r < 4; ++r) {
                float xv = xl[(r0 + r) * 64 + k];
                acc[r][0] = fmaf(xv, w4.x, acc[r][0]);
                acc[r][1] = fmaf(xv, w4.y, acc[r][1]);
                acc[r][2] = fmaf(xv, w4.z, acc[r][2]);
                acc[r][3] = fmaf(xv, w4.w, acc[r][3]);
            }
        }
    }
    // store h rows as fp16, slice-major layout
#pragma unroll
    for (int r = 0; r < 4; ++r) {
        int gr = row0 + r0 + r;
        if (gr < N) {
            __half2 q0 = __floats2half2_rn(acc[r][0], acc[r][1]);
            __half2 q1 = __floats2half2_rn(acc[r][2], acc[r][3]);
            uint2 st;
            st.x = *(unsigned*)&q0;
            st.y = *(unsigned*)&q1;
            *(uint2*)&h[((size_t)(c0 >> 5) * N + gr) * 32 + (c0 & 31)] = st;
        }
    }
    // fused alpha (fp32, pre-rounding)
    float4 asv = *(const float4*)&a_src[c0];
    float4 adv = *(const float4*)&a_dst[c0];
#pragma unroll
    for (int r = 0; r < 4; ++r) {
        float sp = acc[r][0] * asv.x + acc[r][1] * asv.y + acc[r][2] * asv.z +
                   acc[r][3] * asv.w;
        float dp = acc[r][0] * adv.x + acc[r][1] * adv.y + acc[r][2] * adv.z +
                   acc[r][3] * adv.w;
        sp += __shfl_xor(sp, 1, 64);
        sp += __shfl_xor(sp, 2, 64);
        dp += __shfl_xor(dp, 1, 64);
        dp += __shfl_xor(dp, 2, 64);
        int gr = row0 + r0 + r;
        if ((tid & 3) == 0 && gr < N) {
            int hd = (tid & 31) >> 2;
            as[(size_t)gr * 8 + hd] = sp;
            ad[(size_t)gr * 8 + hd] = dp;
        }
    }
}

// ---- pass B: per-bucket LDS CSR build, coalesced write-out ---------------------
__global__ __launch_bounds__(256) void k_csr2(const unsigned* __restrict__ bbuf,
                                              const int* __restrict__ gcnt, int N,
                                              int* __restrict__ deg,
                                              unsigned short* __restrict__ srcs) {
    __shared__ unsigned short rows[256 * CAP];   // 48 KB
    __shared__ int cnt[256];
    const int b = blockIdx.x, tid = threadIdx.x;
    cnt[tid] = 0;
    __syncthreads();
    int nb = gcnt[b];
    const unsigned* bp = &bbuf[(size_t)b * BCAP];
    for (int i = tid; i < nb; i += 256) {
        unsigned u = bp[i];
        int dlo = u >> 16;
        int k = atomicAdd(&cnt[dlo], 1);
        rows[dlo * CAP + k] = (unsigned short)(u & 0xFFFFu);
    }
    __syncthreads();
    int n = (b << 8) + tid;
    if (n < N) deg[n] = cnt[tid];
    int maxn = N - (b << 8);
    if (maxn > 256) maxn = 256;
    if (maxn < 0) maxn = 0;
    const unsigned* r32 = (const unsigned*)rows;
    unsigned* g32 = (unsigned*)srcs;
    size_t gbase = (size_t)(b << 8) * (CAP / 2);
    int lim = maxn * (CAP / 2);
    for (int i = tid; i < lim; i += 256) g32[gbase + i] = r32[i];
}

// ---- Layer 1 aggregate, ONE 32-channel slice (L2-resident gather table) --------
// lane = g*4 + j: g = edge-group 0..15, j = channel block (8 ch via uint4).
// p-phase per 32-edge half: lane = es*2 + hp computes p(edge es, head hp).
__global__ __launch_bounds__(256) void k_agg1s(const int* __restrict__ deg,
                                               const unsigned short* __restrict__ srcs,
                                               const float* __restrict__ as1,
                                               const float* __restrict__ ad1,
                                               const __half* __restrict__ h1s,
                                               const float* __restrict__ b1,
                                               __half* __restrict__ hout, int N,
                                               int slice) {
    int wid = threadIdx.x >> 6, lane = threadIdx.x & 63;
    int n = blockIdx.x * 4 + wid;
    if (n >= N) return;
    size_t st = (size_t)n * CAP;
    int tot = deg[n] + 1;            // + self loop (logical index tot-1)
    int g = lane >> 2;               // edge group 0..15
    int j = lane & 3;                // channel block (8 ch)
    int es = lane >> 1;              // p-phase edge 0..31
    int hp = lane & 1;               // p-phase head within slice
    int hh = j >> 1;                 // consume head within slice
    float adv = ad1[(size_t)n * 8 + slice * 2 + hp];
    const __half* hs = h1s + (size_t)slice * N * 32;
    float l = 0.f;
    float acc[8];
#pragma unroll
    for (int k = 0; k < 8; ++k) acc[k] = 0.f;

    for (int base = 0; base < tot; base += 64) {
        int rem = tot - base;
        if (rem > 64) rem = 64;
        int gi = base + lane;
        int sreg = (gi < tot - 1) ? (int)srcs[st + gi] : n;  // tot-1 -> self loop
        for (int hb = 0; hb < rem; hb += 32) {
            // p-phase: 32 edges x 2 heads, one exp each, tail-zeroed
            int sp = __shfl(sreg, hb + es, 64);
            float pv = __expf(lrelu(as1[(size_t)sp * 8 + slice * 2 + hp] + adv));
            if (hb + es >= rem) pv = 0.f;
            l += pv;
            int lim = rem - hb;
            if (lim > 32) lim = 32;
            for (int t = 0; t < lim; t += 16) {
                int er = t + g;                          // edge 0..31 within half
                int s = __shfl(sreg, hb + er, 64);
                float p = __shfl(pv, (er << 1) | hh, 64);  // 0 beyond lim
                uint4 u = *(const uint4*)&hs[(size_t)s * 32 + (j << 3)];
                const __half2* hp2 = (const __half2*)&u;
#pragma unroll
                for (int k2 = 0; k2 < 4; ++k2) {
                    float2 f = __half22float2(hp2[k2]);
                    acc[2 * k2]     = fmaf(p, f.x, acc[2 * k2]);
                    acc[2 * k2 + 1] = fmaf(p, f.y, acc[2 * k2 + 1]);
                }
            }
        }
    }
    // reduce acc over edge groups g (lane bits 2..5)
#pragma unroll
    for (int k = 0; k < 8; ++k) {
        acc[k] += __shfl_xor(acc[k], 4, 64);
        acc[k] += __shfl_xor(acc[k], 8, 64);
        acc[k] += __shfl_xor(acc[k], 16, 64);
        acc[k] += __shfl_xor(acc[k], 32, 64);
    }
    // reduce l over edges (lane bits 1..5); lane0 = head0, lane1 = head1
    l += __shfl_xor(l, 2, 64);
    l += __shfl_xor(l, 4, 64);
    l += __shfl_xor(l, 8, 64);
    l += __shfl_xor(l, 16, 64);
    l += __shfl_xor(l, 32, 64);
    float lh = __shfl(l, hh, 64);
    if (g == 0) {
        float rl = 1.f / (lh + EPSV);
        int cb = slice * 32 + (j << 3);
        float4 bb0 = *(const float4*)&b1[cb];
        float4 bb1 = *(const float4*)&b1[cb + 4];
        float o[8];
        o[0] = eluf(fmaf(acc[0], rl, bb0.x));
        o[1] = eluf(fmaf(acc[1], rl, bb0.y));
        o[2] = eluf(fmaf(acc[2], rl, bb0.z));
        o[3] = eluf(fmaf(acc[3], rl, bb0.w));
        o[4] = eluf(fmaf(acc[4], rl, bb1.x));
        o[5] = eluf(fmaf(acc[5], rl, bb1.y));
        o[6] = eluf(fmaf(acc[6], rl, bb1.z));
        o[7] = eluf(fmaf(acc[7], rl, bb1.w));
        __half2 q0 = __floats2half2_rn(o[0], o[1]);
        __half2 q1 = __floats2half2_rn(o[2], o[3]);
        __half2 q2 = __floats2half2_rn(o[4], o[5]);
        __half2 q3 = __floats2half2_rn(o[6], o[7]);
        uint4 stv;
        stv.x = *(unsigned*)&q0;
        stv.y = *(unsigned*)&q1;
        stv.z = *(unsigned*)&q2;
        stv.w = *(unsigned*)&q3;
        *(uint4*)&hout[(size_t)n * 128 + cb] = stv;
    }
}

// ------- Layer 2 GEMM + alpha2: fp16 input, 16 rows/block, 4 rows/wave ----------
__global__ __launch_bounds__(256) void k_gemm2(const __half* __restrict__ hin,
                                               const float* __restrict__ W2,
                                               const float* __restrict__ a2s,
                                               const float* __restrict__ a2d,
                                               __half* __restrict__ h2,
                                               float* __restrict__ as2,
                                               float* __restrict__ ad2, int N) {
    __shared__ float wl[128 * 40];   // 20 KB
    __shared__ float xl[16 * 128];   // 8 KB
    const int tid = threadIdx.x;
    const int n0 = blockIdx.x * 16;
#pragma unroll
    for (int i = tid * 4; i < 128 * 40; i += 1024)
        *(float4*)&wl[i] = *(const float4*)&W2[i];
    {
        int i = tid * 8;                 // half index; 256*8 = 2048 = 16*128
        int r = i >> 7;
        int gr = n0 + r;
        float4 v0 = make_float4(0.f, 0.f, 0.f, 0.f);
        float4 v1 = v0;
        if (gr < N) {
            uint4 u = *(const uint4*)&hin[(size_t)gr * 128 + (i & 127)];
            float2 f0 = __half22float2(*(const __half2*)&u.x);
            float2 f1 = __half22float2(*(const __half2*)&u.y);
            float2 f2 = __half22float2(*(const __half2*)&u.z);
            float2 f3 = __half22float2(*(const __half2*)&u.w);
            v0 = make_float4(f0.x, f0.y, f1.x, f1.y);
            v1 = make_float4(f2.x, f2.y, f3.x, f3.y);
        }
        *(float4*)&xl[i] = v0;
        *(float4*)&xl[i + 4] = v1;
    }
    __syncthreads();
    const int w = tid >> 6, c = tid & 63;
    const int r0 = w * 4;
    float a0 = 0.f, a1 = 0.f, a2 = 0.f, a3 = 0.f;
    if (c < 40) {
        const float* x0 = &xl[(r0 + 0) * 128];
        const float* x1 = &xl[(r0 + 1) * 128];
        const float* x2 = &xl[(r0 + 2) * 128];
        const float* x3 = &xl[(r0 + 3) * 128];
#pragma unroll 8
        for (int k = 0; k < 128; k += 4) {
            float4 q0 = *(const float4*)&x0[k];
            float4 q1 = *(const float4*)&x1[k];
            float4 q2 = *(const float4*)&x2[k];
            float4 q3 = *(const float4*)&x3[k];
            float w0 = wl[(k + 0) * 40 + c];
            float w1 = wl[(k + 1) * 40 + c];
            float w2v = wl[(k + 2) * 40 + c];
            float w3 = wl[(k + 3) * 40 + c];
            a0 = fmaf(q0.x, w0, a0); a0 = fmaf(q0.y, w1, a0);
            a0 = fmaf(q0.z, w2v, a0); a0 = fmaf(q0.w, w3, a0);
            a1 = fmaf(q1.x, w0, a1); a1 = fmaf(q1.y, w1, a1);
            a1 = fmaf(q1.z, w2v, a1); a1 = fmaf(q1.w, w3, a1);
            a2 = fmaf(q2.x, w0, a2); a2 = fmaf(q2.y, w1, a2);
            a2 = fmaf(q2.z, w2v, a2); a2 = fmaf(q2.w, w3, a2);
            a3 = fmaf(q3.x, w0, a3); a3 = fmaf(q3.y, w1, a3);
            a3 = fmaf(q3.z, w2v, a3); a3 = fmaf(q3.w, w3, a3);
        }
    }
    float s2v = (c < 40) ? a2s[c] : 0.f;
    float d2v = (c < 40) ? a2d[c] : 0.f;
    float sv0 = a0 * s2v, dv0 = a0 * d2v;
    float sv1 = a1 * s2v, dv1 = a1 * d2v;
    float sv2 = a2 * s2v, dv2 = a2 * d2v;
    float sv3 = a3 * s2v, dv3 = a3 * d2v;
#pragma unroll
    for (int o = 32; o > 0; o >>= 1) {
        sv0 += __shfl_down(sv0, o, 64);
        dv0 += __shfl_down(dv0, o, 64);
        sv1 += __shfl_down(sv1, o, 64);
        dv1 += __shfl_down(dv1, o, 64);
        sv2 += __shfl_down(sv2, o, 64);
        dv2 += __shfl_down(dv2, o, 64);
        sv3 += __shfl_down(sv3, o, 64);
        dv3 += __shfl_down(dv3, o, 64);
    }
    int g0 = n0 + r0, g1 = g0 + 1, g2 = g0 + 2, g3 = g0 + 3;
    if (c < 40) {
        if (g0 < N) h2[(size_t)g0 * 40 + c] = __float2half(a0);
        if (g1 < N) h2[(size_t)g1 * 40 + c] = __float2half(a1);
        if (g2 < N) h2[(size_t)g2 * 40 + c] = __float2half(a2);
        if (g3 < N) h2[(size_t)g3 * 40 + c] = __float2half(a3);
    }
    if (c == 0) {
        if (g0 < N) { as2[g0] = sv0; ad2[g0] = dv0; }
        if (g1 < N) { as2[g1] = sv1; ad2[g1] = dv1; }
        if (g2 < N) { as2[g2] = sv2; ad2[g2] = dv2; }
        if (g3 < N) { as2[g3] = sv3; ad2[g3] = dv3; }
    }
}

// ---- Layer 2 aggregate: p-batch, 8 edges/iter (4 indep chains) -----------------
__global__ __launch_bounds__(256) void k_agg2(const int* __restrict__ deg,
                                              const unsigned short* __restrict__ srcs,
                                              const float* __restrict__ as2,
                                              const float* __restrict__ ad2,
                                              const __half* __restrict__ h2,
                                              const float* __restrict__ b2,
                                              float* __restrict__ out, int N) {
    int wid = threadIdx.x >> 6, lane = threadIdx.x & 63;
    int n = blockIdx.x * 4 + wid;
    if (n >= N) return;
    size_t st = (size_t)n * CAP;
    int tot = deg[n] + 1;
    int half = lane >> 5;
    int cl = lane & 31;
    int c0 = cl * 2;
    float adv = ad2[n];
    float l = 0.f;
    float2 acc = make_float2(0.f, 0.f);

    for (int base = 0; base < tot; base += 64) {
        int rem = tot - base;
        if (rem > 64) rem = 64;
        int gi = base + lane;
        int sreg = (gi < tot - 1) ? (int)srcs[st + gi] : n;
        float pv = 0.f;
        if (gi < tot) pv = __expf(lrelu(as2[sreg] + adv));
        l += pv;
        for (int t = 0; t < rem; t += 8) {
            int s_[4];
            float p_[4];
#pragma unroll
            for (int pr = 0; pr < 4; ++pr) {
                int myi = t + 2 * pr + half;
                int ii = myi & 63;
                s_[pr] = __shfl(sreg, ii, 64);
                float pp = __shfl(pv, ii, 64);   // pv==0 beyond tot
                if (myi >= 64) pp = 0.f;         // wrapped index: force zero
                p_[pr] = pp;
            }
            if (cl < 20) {
#pragma unroll
                for (int pr = 0; pr < 4; ++pr) {
                    float2 hv =
                        __half22float2(*(const __half2*)&h2[(size_t)s_[pr] * 40 + c0]);
                    acc.x = fmaf(p_[pr], hv.x, acc.x);
                    acc.y = fmaf(p_[pr], hv.y, acc.y);
                }
            }
        }
    }
#pragma unroll
    for (int off = 1; off < 64; off <<= 1) l += __shfl_xor(l, off, 64);
    acc.x += __shfl_xor(acc.x, 32, 64);
    acc.y += __shfl_xor(acc.y, 32, 64);
    if (half == 0 && cl < 20) {
        float rl = 1.f / (l + EPSV);
        out[(size_t)n * 40 + c0]     = fmaf(acc.x, rl, b2[c0]);
        out[(size_t)n * 40 + c0 + 1] = fmaf(acc.y, rl, b2[c0 + 1]);
    }
}

extern "C" void kernel_launch(void* const* d_in, const int* in_sizes, int n_in,
                              void* d_out, int out_size, void* d_ws, size_t ws_size,
                              hipStream_t stream) {
    const float* x      = (const float*)d_in[0];
    const int*   ei     = (const int*)d_in[1];
    const float* W1     = (const float*)d_in[2];
    const float* a_src1 = (const float*)d_in[3];
    const float* a_dst1 = (const float*)d_in[4];
    const float* b1     = (const float*)d_in[5];
    const float* W2     = (const float*)d_in[6];
    const float* a_src2 = (const float*)d_in[7];
    const float* a_dst2 = (const float*)d_in[8];
    const float* b2     = (const float*)d_in[9];
    float* out = (float*)d_out;

    const int N = in_sizes[0] / 128;
    const int E = in_sizes[1] / 2;
    const int AB = (E + CHUNK - 1) / CHUNK;
    const int GB = (N + 31) / 32;
    const int NBUCK = (N + 255) >> 8;

    float* ws = (float*)d_ws;
    size_t off = 0;
    auto alloc = [&](size_t nElem) {
        float* p = ws + off;
        off += (nElem + 3) & ~(size_t)3;
        return p;
    };
    __half* h1           = (__half*)alloc((size_t)N * 64);   // 4 slices x N x 32 fp16
    __half* hin2         = (__half*)alloc((size_t)N * 64);   // N*128 halves (fp16)
    float* as1           = alloc((size_t)N * 8);
    float* ad1           = alloc((size_t)N * 8);
    __half* h2           = (__half*)alloc((size_t)N * 20);   // N*40 halves
    float* as2           = alloc(N);
    float* ad2           = alloc(N);
    int* deg             = (int*)alloc(N);                   // fully overwritten by k_csr2
    int* gcur            = (int*)alloc(256);
    unsigned short* srcs = (unsigned short*)alloc(((size_t)N * CAP + 1) / 2);
    unsigned* bbuf       = (unsigned*)alloc((size_t)NBUCK * BCAP);

    // only gcur needs zeroing: k_csr2 writes every deg[n] unconditionally
    hipMemsetAsync(gcur, 0, 256 * sizeof(int), stream);

    dim3 B(256);
    k_fused1<<<dim3(AB + GB), B, 0, stream>>>(x, W1, a_src1, a_dst1, ei, E, N, AB,
                                              h1, as1, ad1, gcur, bbuf);
    k_csr2<<<dim3(NBUCK), B, 0, stream>>>(bbuf, gcur, N, deg, srcs);
    for (int s = 0; s < 4; ++s)
        k_agg1s<<<dim3((N + 3) / 4), B, 0, stream>>>(deg, srcs, as1, ad1, h1, b1,
                                                     hin2, N, s);
    k_gemm2<<<dim3((N + 15) / 16), B, 0, stream>>>(hin2, W2, a_src2, a_dst2, h2, as2, ad2, N);
    k_agg2<<<dim3((N + 3) / 4), B, 0, stream>>>(deg, srcs, as2, ad2, h2, b2, out, N);
}

// Round 15
// 181.787 us; speedup vs baseline: 1.4050x; 1.4050x over previous
//
#include <hip/hip_runtime.h>
#include <hip/hip_bf16.h>
#include <hip/hip_fp16.h>

#define NEG_SLOPE 0.2f
#define EPSV 1e-16f
#define CAP 96            // padded CSR row capacity (deg ~ Poisson(32))
#define CHUNK 4096        // edges per pass-A build block
#define BCAP 9216         // bucket capacity in edges (mean 8163, +11 sigma)

static __device__ __forceinline__ float lrelu(float v) {
    return v > 0.0f ? v : NEG_SLOPE * v;
}
static __device__ __forceinline__ float eluf(float v) {
    return v > 0.0f ? v : (__expf(v) - 1.0f);
}

// ---- fused: [0..AB): bucket pass A | [AB..AB+GB): gemm1 + alpha1 --------------
// kt=32 tiling: 20 KB LDS -> 8 blocks/CU (occupancy for the latency-bound build).
__global__ __launch_bounds__(256) void k_fused1(
    const float* __restrict__ x, const float* __restrict__ W,
    const float* __restrict__ a_src, const float* __restrict__ a_dst,
    const int* __restrict__ ei, int E, int N, int AB,
    __half* __restrict__ h, float* __restrict__ as, float* __restrict__ ad,
    int* __restrict__ gcur, unsigned* __restrict__ bbuf) {
    __shared__ float wl[32 * 128];   // 16 KB
    __shared__ float xl[32 * 32];    // 4 KB
    const int tid = threadIdx.x;

    if ((int)blockIdx.x < AB) {
        // ---- pass A: reg-cached src+dst -> count -> reserve -> run-writes ------
        int* cnt = (int*)wl;
        int* base = ((int*)wl) + 256;
        int e0 = blockIdx.x * CHUNK;
        int dreg[16], sreg[16];
#pragma unroll
        for (int jj = 0; jj < 16; ++jj) {
            int e = e0 + tid + jj * 256;
            dreg[jj] = (e < E) ? ei[E + e] : -1;
            sreg[jj] = (e < E) ? ei[e] : 0;
        }
        cnt[tid] = 0;
        __syncthreads();
#pragma unroll
        for (int jj = 0; jj < 16; ++jj)
            if (dreg[jj] >= 0) atomicAdd(&cnt[dreg[jj] >> 8], 1);
        __syncthreads();
        {
            int c = cnt[tid];
            base[tid] = c ? atomicAdd(&gcur[tid], c) : 0;
            cnt[tid] = 0;
        }
        __syncthreads();
#pragma unroll
        for (int jj = 0; jj < 16; ++jj) {
            int d = dreg[jj];
            if (d >= 0) {
                int b = d >> 8;
                int k = atomicAdd(&cnt[b], 1);
                bbuf[(size_t)b * BCAP + base[b] + k] =
                    (unsigned)sreg[jj] | ((unsigned)(d & 255) << 16);
            }
        }
        return;
    }

    // ---- gemm branch: h[32 rows x 128] = x @ W, + per-head logits --------------
    const int row0 = (blockIdx.x - AB) * 32;
    const int c0 = (tid & 31) * 4;
    const int r0 = (tid >> 5) * 4;
    float acc[4][4];
#pragma unroll
    for (int r = 0; r < 4; ++r)
#pragma unroll
        for (int c = 0; c < 4; ++c) acc[r][c] = 0.0f;

    for (int kt = 0; kt < 128; kt += 32) {
        __syncthreads();
#pragma unroll
        for (int i = tid * 4; i < 32 * 128; i += 1024)
            *(float4*)&wl[i] = *(const float4*)&W[kt * 128 + i];
        {
            int i = tid * 4;                 // 1024 floats = 32 rows x 32 cols
            int r = i >> 5, c = i & 31;
            int gr = row0 + r;
            float4 v = make_float4(0.f, 0.f, 0.f, 0.f);
            if (gr < N) v = *(const float4*)&x[(size_t)gr * 128 + kt + c];
            *(float4*)&xl[i] = v;
        }
        __syncthreads();
#pragma unroll 8
        for (int k = 0; k < 32; ++k) {
            float4 w4 = *(const float4*)&wl[k * 128 + c0];
#pragma unroll
            for (int r = 0; r < 4; ++r) {
                float xv = xl[(r0 + r) * 32 + k];
                acc[r][0] = fmaf(xv, w4.x, acc[r][0]);
                acc[r][1] = fmaf(xv, w4.y, acc[r][1]);
                acc[r][2] = fmaf(xv, w4.z, acc[r][2]);
                acc[r][3] = fmaf(xv, w4.w, acc[r][3]);
            }
        }
    }
    // store h rows as fp16 (row-major)
#pragma unroll
    for (int r = 0; r < 4; ++r) {
        int gr = row0 + r0 + r;
        if (gr < N) {
            __half2 q0 = __floats2half2_rn(acc[r][0], acc[r][1]);
            __half2 q1 = __floats2half2_rn(acc[r][2], acc[r][3]);
            uint2 st;
            st.x = *(unsigned*)&q0;
            st.y = *(unsigned*)&q1;
            *(uint2*)&h[(size_t)gr * 128 + c0] = st;
        }
    }
    // fused alpha (fp32, pre-rounding)
    float4 asv = *(const float4*)&a_src[c0];
    float4 adv = *(const float4*)&a_dst[c0];
#pragma unroll
    for (int r = 0; r < 4; ++r) {
        float sp = acc[r][0] * asv.x + acc[r][1] * asv.y + acc[r][2] * asv.z +
                   acc[r][3] * asv.w;
        float dp = acc[r][0] * adv.x + acc[r][1] * adv.y + acc[r][2] * adv.z +
                   acc[r][3] * adv.w;
        sp += __shfl_xor(sp, 1, 64);
        sp += __shfl_xor(sp, 2, 64);
        dp += __shfl_xor(dp, 1, 64);
        dp += __shfl_xor(dp, 2, 64);
        int gr = row0 + r0 + r;
        if ((tid & 3) == 0 && gr < N) {
            int hd = (tid & 31) >> 2;
            as[(size_t)gr * 8 + hd] = sp;
            ad[(size_t)gr * 8 + hd] = dp;
        }
    }
}

// ---- pass B: per-bucket LDS CSR build, coalesced write-out ---------------------
__global__ __launch_bounds__(256) void k_csr2(const unsigned* __restrict__ bbuf,
                                              const int* __restrict__ gcnt, int N,
                                              int* __restrict__ deg,
                                              unsigned short* __restrict__ srcs) {
    __shared__ unsigned short rows[256 * CAP];   // 48 KB
    __shared__ int cnt[256];
    const int b = blockIdx.x, tid = threadIdx.x;
    cnt[tid] = 0;
    __syncthreads();
    int nb = gcnt[b];
    const unsigned* bp = &bbuf[(size_t)b * BCAP];
    for (int i = tid; i < nb; i += 256) {
        unsigned u = bp[i];
        int dlo = u >> 16;
        int k = atomicAdd(&cnt[dlo], 1);
        rows[dlo * CAP + k] = (unsigned short)(u & 0xFFFFu);
    }
    __syncthreads();
    int n = (b << 8) + tid;
    if (n < N) deg[n] = cnt[tid];
    int maxn = N - (b << 8);
    if (maxn > 256) maxn = 256;
    if (maxn < 0) maxn = 0;
    const unsigned* r32 = (const unsigned*)rows;
    unsigned* g32 = (unsigned*)srcs;
    size_t gbase = (size_t)(b << 8) * (CAP / 2);
    int lim = maxn * (CAP / 2);
    for (int i = tid; i < lim; i += 256) g32[gbase + i] = r32[i];
}

// ---- Layer 1 aggregate: p-batch, uint4 fp16 gather, fp16 output ----------------
__global__ __launch_bounds__(256) void k_agg1(const int* __restrict__ deg,
                                              const unsigned short* __restrict__ srcs,
                                              const float* __restrict__ as1,
                                              const float* __restrict__ ad1,
                                              const __half* __restrict__ h1,
                                              const float* __restrict__ b1,
                                              __half* __restrict__ hout, int N) {
    int wid = threadIdx.x >> 6, lane = threadIdx.x & 63;
    int n = blockIdx.x * 4 + wid;
    if (n >= N) return;
    size_t st = (size_t)n * CAP;
    int tot = deg[n] + 1;            // + self loop (logical index tot-1)
    int q = lane >> 4;               // quarter 0..3
    int j = lane & 15;               // channel block
    int es = lane >> 3;              // p-phase edge slot 0..7
    int hq = lane & 7;               // p-phase head
    float adv = ad1[(size_t)n * 8 + hq];
    float l = 0.f;
    float acc[8];
#pragma unroll
    for (int k = 0; k < 8; ++k) acc[k] = 0.f;

    for (int base = 0; base < tot; base += 64) {
        int rem = tot - base;
        if (rem > 64) rem = 64;
        int gi = base + lane;
        int sreg = (gi < tot - 1) ? (int)srcs[st + gi] : n;  // tot-1 -> self loop
        for (int bb = 0; bb < rem; bb += 8) {
            int sp = __shfl(sreg, bb + es, 64);
            float pv = __expf(lrelu(as1[(size_t)sp * 8 + hq] + adv));
            if (bb + es >= rem) pv = 0.f;
            l += pv;
#pragma unroll
            for (int t = 0; t < 8; t += 4) {
                int er = t + q;
                int s = __shfl(sreg, bb + er, 64);
                float p = __shfl(pv, (er << 3) | (j >> 1), 64);
                uint4 u = *(const uint4*)&h1[(size_t)s * 128 + (j << 3)];
                const __half2* hp2 = (const __half2*)&u;
#pragma unroll
                for (int k2 = 0; k2 < 4; ++k2) {
                    float2 f = __half22float2(hp2[k2]);
                    acc[2 * k2]     = fmaf(p, f.x, acc[2 * k2]);
                    acc[2 * k2 + 1] = fmaf(p, f.y, acc[2 * k2 + 1]);
                }
            }
        }
    }
#pragma unroll
    for (int k = 0; k < 8; ++k) {
        acc[k] += __shfl_xor(acc[k], 16, 64);
        acc[k] += __shfl_xor(acc[k], 32, 64);
    }
    l += __shfl_xor(l, 8, 64);
    l += __shfl_xor(l, 16, 64);
    l += __shfl_xor(l, 32, 64);
    float myl = __shfl(l, j >> 1, 64);
    if (q == 0) {
        float rl = 1.f / (myl + EPSV);
        float4 bb0 = *(const float4*)&b1[j * 8];
        float4 bb1 = *(const float4*)&b1[j * 8 + 4];
        float o[8];
        o[0] = eluf(fmaf(acc[0], rl, bb0.x));
        o[1] = eluf(fmaf(acc[1], rl, bb0.y));
        o[2] = eluf(fmaf(acc[2], rl, bb0.z));
        o[3] = eluf(fmaf(acc[3], rl, bb0.w));
        o[4] = eluf(fmaf(acc[4], rl, bb1.x));
        o[5] = eluf(fmaf(acc[5], rl, bb1.y));
        o[6] = eluf(fmaf(acc[6], rl, bb1.z));
        o[7] = eluf(fmaf(acc[7], rl, bb1.w));
        __half2 q0 = __floats2half2_rn(o[0], o[1]);
        __half2 q1 = __floats2half2_rn(o[2], o[3]);
        __half2 q2 = __floats2half2_rn(o[4], o[5]);
        __half2 q3 = __floats2half2_rn(o[6], o[7]);
        uint4 stv;
        stv.x = *(unsigned*)&q0;
        stv.y = *(unsigned*)&q1;
        stv.z = *(unsigned*)&q2;
        stv.w = *(unsigned*)&q3;
        *(uint4*)&hout[(size_t)n * 128 + j * 8] = stv;
    }
}

// ------- Layer 2 GEMM + alpha2: fp16 input, 16 rows/block, 4 rows/wave ----------
__global__ __launch_bounds__(256) void k_gemm2(const __half* __restrict__ hin,
                                               const float* __restrict__ W2,
                                               const float* __restrict__ a2s,
                                               const float* __restrict__ a2d,
                                               __half* __restrict__ h2,
                                               float* __restrict__ as2,
                                               float* __restrict__ ad2, int N) {
    __shared__ float wl[128 * 40];   // 20 KB
    __shared__ float xl[16 * 128];   // 8 KB
    const int tid = threadIdx.x;
    const int n0 = blockIdx.x * 16;
#pragma unroll
    for (int i = tid * 4; i < 128 * 40; i += 1024)
        *(float4*)&wl[i] = *(const float4*)&W2[i];
    {
        int i = tid * 8;                 // half index; 256*8 = 2048 = 16*128
        int r = i >> 7;
        int gr = n0 + r;
        float4 v0 = make_float4(0.f, 0.f, 0.f, 0.f);
        float4 v1 = v0;
        if (gr < N) {
            uint4 u = *(const uint4*)&hin[(size_t)gr * 128 + (i & 127)];
            float2 f0 = __half22float2(*(const __half2*)&u.x);
            float2 f1 = __half22float2(*(const __half2*)&u.y);
            float2 f2 = __half22float2(*(const __half2*)&u.z);
            float2 f3 = __half22float2(*(const __half2*)&u.w);
            v0 = make_float4(f0.x, f0.y, f1.x, f1.y);
            v1 = make_float4(f2.x, f2.y, f3.x, f3.y);
        }
        *(float4*)&xl[i] = v0;
        *(float4*)&xl[i + 4] = v1;
    }
    __syncthreads();
    const int w = tid >> 6, c = tid & 63;
    const int r0 = w * 4;
    float a0 = 0.f, a1 = 0.f, a2 = 0.f, a3 = 0.f;
    if (c < 40) {
        const float* x0 = &xl[(r0 + 0) * 128];
        const float* x1 = &xl[(r0 + 1) * 128];
        const float* x2 = &xl[(r0 + 2) * 128];
        const float* x3 = &xl[(r0 + 3) * 128];
#pragma unroll 8
        for (int k = 0; k < 128; k += 4) {
            float4 q0 = *(const float4*)&x0[k];
            float4 q1 = *(const float4*)&x1[k];
            float4 q2 = *(const float4*)&x2[k];
            float4 q3 = *(const float4*)&x3[k];
            float w0 = wl[(k + 0) * 40 + c];
            float w1 = wl[(k + 1) * 40 + c];
            float w2v = wl[(k + 2) * 40 + c];
            float w3 = wl[(k + 3) * 40 + c];
            a0 = fmaf(q0.x, w0, a0); a0 = fmaf(q0.y, w1, a0);
            a0 = fmaf(q0.z, w2v, a0); a0 = fmaf(q0.w, w3, a0);
            a1 = fmaf(q1.x, w0, a1); a1 = fmaf(q1.y, w1, a1);
            a1 = fmaf(q1.z, w2v, a1); a1 = fmaf(q1.w, w3, a1);
            a2 = fmaf(q2.x, w0, a2); a2 = fmaf(q2.y, w1, a2);
            a2 = fmaf(q2.z, w2v, a2); a2 = fmaf(q2.w, w3, a2);
            a3 = fmaf(q3.x, w0, a3); a3 = fmaf(q3.y, w1, a3);
            a3 = fmaf(q3.z, w2v, a3); a3 = fmaf(q3.w, w3, a3);
        }
    }
    float s2v = (c < 40) ? a2s[c] : 0.f;
    float d2v = (c < 40) ? a2d[c] : 0.f;
    float sv0 = a0 * s2v, dv0 = a0 * d2v;
    float sv1 = a1 * s2v, dv1 = a1 * d2v;
    float sv2 = a2 * s2v, dv2 = a2 * d2v;
    float sv3 = a3 * s2v, dv3 = a3 * d2v;
#pragma unroll
    for (int o = 32; o > 0; o >>= 1) {
        sv0 += __shfl_down(sv0, o, 64);
        dv0 += __shfl_down(dv0, o, 64);
        sv1 += __shfl_down(sv1, o, 64);
        dv1 += __shfl_down(dv1, o, 64);
        sv2 += __shfl_down(sv2, o, 64);
        dv2 += __shfl_down(dv2, o, 64);
        sv3 += __shfl_down(sv3, o, 64);
        dv3 += __shfl_down(dv3, o, 64);
    }
    int g0 = n0 + r0, g1 = g0 + 1, g2 = g0 + 2, g3 = g0 + 3;
    if (c < 40) {
        if (g0 < N) h2[(size_t)g0 * 40 + c] = __float2half(a0);
        if (g1 < N) h2[(size_t)g1 * 40 + c] = __float2half(a1);
        if (g2 < N) h2[(size_t)g2 * 40 + c] = __float2half(a2);
        if (g3 < N) h2[(size_t)g3 * 40 + c] = __float2half(a3);
    }
    if (c == 0) {
        if (g0 < N) { as2[g0] = sv0; ad2[g0] = dv0; }
        if (g1 < N) { as2[g1] = sv1; ad2[g1] = dv1; }
        if (g2 < N) { as2[g2] = sv2; ad2[g2] = dv2; }
        if (g3 < N) { as2[g3] = sv3; ad2[g3] = dv3; }
    }
}

// ---- Layer 2 aggregate: p-batch, 8 edges/iter (4 indep chains) -----------------
__global__ __launch_bounds__(256) void k_agg2(const int* __restrict__ deg,
                                              const unsigned short* __restrict__ srcs,
                                              const float* __restrict__ as2,
                                              const float* __restrict__ ad2,
                                              const __half* __restrict__ h2,
                                              const float* __restrict__ b2,
                                              float* __restrict__ out, int N) {
    int wid = threadIdx.x >> 6, lane = threadIdx.x & 63;
    int n = blockIdx.x * 4 + wid;
    if (n >= N) return;
    size_t st = (size_t)n * CAP;
    int tot = deg[n] + 1;
    int half = lane >> 5;
    int cl = lane & 31;
    int c0 = cl * 2;
    float adv = ad2[n];
    float l = 0.f;
    float2 acc = make_float2(0.f, 0.f);

    for (int base = 0; base < tot; base += 64) {
        int rem = tot - base;
        if (rem > 64) rem = 64;
        int gi = base + lane;
        int sreg = (gi < tot - 1) ? (int)srcs[st + gi] : n;
        float pv = 0.f;
        if (gi < tot) pv = __expf(lrelu(as2[sreg] + adv));
        l += pv;
        for (int t = 0; t < rem; t += 8) {
            int s_[4];
            float p_[4];
#pragma unroll
            for (int pr = 0; pr < 4; ++pr) {
                int myi = t + 2 * pr + half;
                int ii = myi & 63;
                s_[pr] = __shfl(sreg, ii, 64);
                float pp = __shfl(pv, ii, 64);   // pv==0 beyond tot
                if (myi >= 64) pp = 0.f;         // wrapped index: force zero
                p_[pr] = pp;
            }
            if (cl < 20) {
#pragma unroll
                for (int pr = 0; pr < 4; ++pr) {
                    float2 hv =
                        __half22float2(*(const __half2*)&h2[(size_t)s_[pr] * 40 + c0]);
                    acc.x = fmaf(p_[pr], hv.x, acc.x);
                    acc.y = fmaf(p_[pr], hv.y, acc.y);
                }
            }
        }
    }
#pragma unroll
    for (int off = 1; off < 64; off <<= 1) l += __shfl_xor(l, off, 64);
    acc.x += __shfl_xor(acc.x, 32, 64);
    acc.y += __shfl_xor(acc.y, 32, 64);
    if (half == 0 && cl < 20) {
        float rl = 1.f / (l + EPSV);
        out[(size_t)n * 40 + c0]     = fmaf(acc.x, rl, b2[c0]);
        out[(size_t)n * 40 + c0 + 1] = fmaf(acc.y, rl, b2[c0 + 1]);
    }
}

extern "C" void kernel_launch(void* const* d_in, const int* in_sizes, int n_in,
                              void* d_out, int out_size, void* d_ws, size_t ws_size,
                              hipStream_t stream) {
    const float* x      = (const float*)d_in[0];
    const int*   ei     = (const int*)d_in[1];
    const float* W1     = (const float*)d_in[2];
    const float* a_src1 = (const float*)d_in[3];
    const float* a_dst1 = (const float*)d_in[4];
    const float* b1     = (const float*)d_in[5];
    const float* W2     = (const float*)d_in[6];
    const float* a_src2 = (const float*)d_in[7];
    const float* a_dst2 = (const float*)d_in[8];
    const float* b2     = (const float*)d_in[9];
    float* out = (float*)d_out;

    const int N = in_sizes[0] / 128;
    const int E = in_sizes[1] / 2;
    const int AB = (E + CHUNK - 1) / CHUNK;
    const int GB = (N + 31) / 32;
    const int NBUCK = (N + 255) >> 8;

    float* ws = (float*)d_ws;
    size_t off = 0;
    auto alloc = [&](size_t nElem) {
        float* p = ws + off;
        off += (nElem + 3) & ~(size_t)3;
        return p;
    };
    __half* h1           = (__half*)alloc((size_t)N * 64);   // N*128 halves
    __half* hin2         = (__half*)alloc((size_t)N * 64);   // N*128 halves (fp16)
    float* as1           = alloc((size_t)N * 8);
    float* ad1           = alloc((size_t)N * 8);
    __half* h2           = (__half*)alloc((size_t)N * 20);   // N*40 halves
    float* as2           = alloc(N);
    float* ad2           = alloc(N);
    int* deg             = (int*)alloc(N);                   // fully overwritten by k_csr2
    int* gcur            = (int*)alloc(256);
    unsigned short* srcs = (unsigned short*)alloc(((size_t)N * CAP + 1) / 2);
    unsigned* bbuf       = (unsigned*)alloc((size_t)NBUCK * BCAP);

    // only gcur needs zeroing: k_csr2 writes every deg[n] unconditionally
    hipMemsetAsync(gcur, 0, 256 * sizeof(int), stream);

    dim3 B(256);
    k_fused1<<<dim3(AB + GB), B, 0, stream>>>(x, W1, a_src1, a_dst1, ei, E, N, AB,
                                              h1, as1, ad1, gcur, bbuf);
    k_csr2<<<dim3(NBUCK), B, 0, stream>>>(bbuf, gcur, N, deg, srcs);
    k_agg1<<<dim3((N + 3) / 4), B, 0, stream>>>(deg, srcs, as1, ad1, h1, b1, hin2, N);
    k_gemm2<<<dim3((N + 15) / 16), B, 0, stream>>>(hin2, W2, a_src2, a_dst2, h2, as2, ad2, N);
    k_agg2<<<dim3((N + 3) / 4), B, 0, stream>>>(deg, srcs, as2, ad2, h2, b2, out, N);
}